// Round 1
// baseline (2882.246 us; speedup 1.0000x reference)
//
#include <hip/hip_runtime.h>

// StructLNN: LN(67) -> Linear(67,256)+LN+SiLU -> CfC scan (2048 steps) -> LN head -> [B,S,1]
// Decomposition:
//   prep: repack weights (W_x^T bf16 for GEMM, W_h int8-quantized per-column for scan, head scalars)
//   k2 feat_kernel: input LN + MFMA proj + LN + SiLU -> feat bf16
//   k3 gemm_kernel: pre = feat @ W_x^T + bias4 (bf16 MFMA, 128x128 tile, global_load_lds)
//   k4 scan_kernel: 1 WG per batch, weights resident in VGPRs as int8, sdot4 dots,
//                   head LN+proj folded to 3 reductions -> logit per step.
// S chunked adaptively to fit ws_size (chunks serialize on stream; h state persists in ws).

typedef __bf16 bf16x8 __attribute__((ext_vector_type(8)));
typedef float f32x4 __attribute__((ext_vector_type(4)));

#define DEVFN static __device__ __forceinline__

DEVFN float bf2f(unsigned short u){ return __uint_as_float(((unsigned)u) << 16); }
DEVFN unsigned short f2bf(float f){
  unsigned x = __float_as_uint(f);
  return (unsigned short)((x + 0x7FFFu + ((x >> 16) & 1u)) >> 16);
}
DEVFN float sigm(float x){ return 1.f / (1.f + __expf(-x)); }
DEVFN float tanh_f(float x){ return 1.f - 2.f / (__expf(2.f * x) + 1.f); }

#if __has_builtin(__builtin_amdgcn_sdot4)
DEVFN int dot4i8(int a, int b, int c){ return __builtin_amdgcn_sdot4(a, b, c, false); }
#else
DEVFN int dot4i8(int a, int b, int c){
  c += (int)(signed char)(a & 0xff)        * (int)(signed char)(b & 0xff);
  c += (int)(signed char)((a >> 8) & 0xff) * (int)(signed char)((b >> 8) & 0xff);
  c += (int)(signed char)((a >> 16) & 0xff)* (int)(signed char)((b >> 16) & 0xff);
  c += (a >> 24) * (b >> 24);
  return c;
}
#endif

#define GLD_LDS16(g, l) \
  __builtin_amdgcn_global_load_lds((const __attribute__((address_space(1))) void*)(g), \
                                   (__attribute__((address_space(3))) void*)(l), 16, 0, 0)

static constexpr int BB = 128;
static constexpr int SS = 2048;
static constexpr int DD = 67;

// ws layout (bytes)
static constexpr size_t OFF_WXT   = 0;         // bf16 [1024][256]  W_x^T (x-part of 4 mats)
static constexpr size_t OFF_WQ    = 524288;    // i8   [1024][256]  W_h^T quantized
static constexpr size_t OFF_SW    = 786432;    // f32  [1024] per-column scales
static constexpr size_t OFF_BIAS4 = 790528;    // f32  [1024] concat(b_ff1,b_ff2,b_ta,b_tb)
static constexpr size_t OFF_PWT   = 794624;    // bf16 [256][96] proj_W^T zero-padded
static constexpr size_t OFF_GW    = 843776;    // f32  [256] head_g*head_W
static constexpr size_t OFF_SCAL  = 844800;    // f32  [2]: S_gW, S_bW+head_bias
static constexpr size_t OFF_HST   = 845824;    // i32  [128][64] persisted packed-int8 h
static constexpr size_t OFF_FEAT  = 878592;    // bf16 [B*C][256]

// ---------------------------------------------------------------- prep
__global__ __launch_bounds__(256) void prep_kernel(
    const float* __restrict__ proj_W,
    const float* __restrict__ W_ff1, const float* __restrict__ b_ff1,
    const float* __restrict__ W_ff2, const float* __restrict__ b_ff2,
    const float* __restrict__ W_ta,  const float* __restrict__ b_ta,
    const float* __restrict__ W_tb,  const float* __restrict__ b_tb,
    const float* __restrict__ head_g, const float* __restrict__ head_b,
    const float* __restrict__ head_W, const float* __restrict__ head_bias,
    unsigned short* __restrict__ WxT, signed char* __restrict__ wq,
    float* __restrict__ sw, float* __restrict__ bias4,
    unsigned short* __restrict__ PWT, float* __restrict__ gW, float* __restrict__ scal)
{
  __shared__ float red[8];
  int bid = blockIdx.x, t = threadIdx.x;
  int wv = t >> 6, ln = t & 63;
  if (bid < 1024) {
    int J = bid, col = J & 255, which = J >> 8;
    const float* Wsrc = which == 0 ? W_ff1 : which == 1 ? W_ff2 : which == 2 ? W_ta : W_tb;
    const float* bsrc = which == 0 ? b_ff1 : which == 1 ? b_ff2 : which == 2 ? b_ta : b_tb;
    float w = Wsrc[t * 256 + col];          // x-part rows 0..255
    WxT[J * 256 + t] = f2bf(w);
    if (t == 0) bias4[J] = bsrc[col];
  } else if (bid < 2048) {
    int J = bid - 1024, col = J & 255, which = J >> 8;
    const float* Wsrc = which == 0 ? W_ff1 : which == 1 ? W_ff2 : which == 2 ? W_ta : W_tb;
    float w = Wsrc[(256 + t) * 256 + col];  // h-part rows 256..511
    float a = fabsf(w);
    for (int m = 32; m >= 1; m >>= 1) a = fmaxf(a, __shfl_xor(a, m, 64));
    if (ln == 0) red[wv] = a;
    __syncthreads();
    a = fmaxf(fmaxf(red[0], red[1]), fmaxf(red[2], red[3]));
    float scale = (a > 0.f) ? a * (1.f / 127.f) : 1.f;
    int q = (int)rintf(w / scale);
    q = q > 127 ? 127 : (q < -127 ? -127 : q);
    wq[J * 256 + t] = (signed char)q;
    if (t == 0) sw[J] = scale;
  } else {
    for (int idx = t; idx < 256 * 96; idx += 256) {
      int j = idx / 96, d = idx % 96;
      float v = (d < DD) ? proj_W[d * 256 + j] : 0.f;
      PWT[idx] = f2bf(v);
    }
    float gw = head_g[t] * head_W[t];
    gW[t] = gw;
    float bw = head_b[t] * head_W[t];
    float s1 = gw, s2 = bw;
    for (int m = 32; m >= 1; m >>= 1) { s1 += __shfl_xor(s1, m, 64); s2 += __shfl_xor(s2, m, 64); }
    if (ln == 0) { red[wv] = s1; red[4 + wv] = s2; }
    __syncthreads();
    if (t == 0) {
      scal[0] = red[0] + red[1] + red[2] + red[3];
      scal[1] = red[4] + red[5] + red[6] + red[7] + head_bias[0];
    }
  }
}

// ---------------------------------------------------------------- k2: x -> feat
__global__ __launch_bounds__(512) void feat_kernel(
    const float* __restrict__ x, const float* __restrict__ ln_in_g, const float* __restrict__ ln_in_b,
    const float* __restrict__ proj_b, const float* __restrict__ ln_p_g, const float* __restrict__ ln_p_b,
    const unsigned short* __restrict__ PWT, unsigned short* __restrict__ feat,
    int s0, int C, int cshift)
{
  __shared__ __align__(16) unsigned short XA[64 * 104];  // xn bf16, stride 104 (16B-aligned, 2-way banks)
  __shared__ __align__(16) unsigned short XB[256 * 96];  // proj_W^T padded
  __shared__ float partS[64][4], partQ[64][4], statM[64], statI[64];
  int tid = threadIdx.x, w = tid >> 6, lane = tid & 63;
  int r0 = blockIdx.x * 64;

  // phase 1: input LayerNorm over D=67, write bf16 to XA (cols 67..103 zero)
  {
    float g1v = (lane < 67) ? ln_in_g[lane] : 0.f;
    float b1v = (lane < 67) ? ln_in_b[lane] : 0.f;
    float g2v = (lane < 3) ? ln_in_g[64 + lane] : 0.f;
    float b2v = (lane < 3) ? ln_in_b[64 + lane] : 0.f;
    for (int i = 0; i < 8; ++i) {
      int rl = w * 8 + i;
      int r = r0 + rl;
      int bb = r >> cshift, cs = r & (C - 1);
      const float* xr = x + (size_t)(bb * SS + s0 + cs) * DD;
      float v0 = (lane < 67) ? xr[lane] : 0.f;
      float v1 = (lane < 3) ? xr[64 + lane] : 0.f;
      float s = v0 + v1, q = v0 * v0 + v1 * v1;
      for (int m = 32; m >= 1; m >>= 1) { s += __shfl_xor(s, m, 64); q += __shfl_xor(q, m, 64); }
      float mean = s * (1.f / 67.f);
      float var = q * (1.f / 67.f) - mean * mean;
      float inv = rsqrtf(var + 1e-5f);
      float xn0 = (v0 - mean) * inv * g1v + b1v;
      float xn1 = (v1 - mean) * inv * g2v + b2v;
      XA[rl * 104 + lane] = (lane < 67) ? f2bf(xn0) : (unsigned short)0;
      if (lane < 40) XA[rl * 104 + 64 + lane] = (lane < 3) ? f2bf(xn1) : (unsigned short)0;
    }
  }
  // stage proj_W^T
  {
    const unsigned int* src = (const unsigned int*)PWT;
    unsigned int* dst = (unsigned int*)XB;
    for (int idx = tid; idx < 256 * 48; idx += 512) dst[idx] = src[idx];
  }
  __syncthreads();

  // phase 2: MFMA [64x96]@[96x256]
  int wm = w >> 2, wn = w & 3;
  f32x4 acc[2][4];
  #pragma unroll
  for (int mt = 0; mt < 2; ++mt)
    #pragma unroll
    for (int nt = 0; nt < 4; ++nt) acc[mt][nt] = (f32x4){0.f, 0.f, 0.f, 0.f};
  #pragma unroll
  for (int ks = 0; ks < 3; ++ks) {
    int k = ks * 32 + (lane >> 4) * 8;
    bf16x8 a[2], b[4];
    #pragma unroll
    for (int mt = 0; mt < 2; ++mt) {
      int row = wm * 32 + mt * 16 + (lane & 15);
      a[mt] = *reinterpret_cast<const bf16x8*>(&XA[row * 104 + k]);
    }
    #pragma unroll
    for (int nt = 0; nt < 4; ++nt) {
      int col = wn * 64 + nt * 16 + (lane & 15);
      b[nt] = *reinterpret_cast<const bf16x8*>(&XB[col * 96 + k]);
    }
    #pragma unroll
    for (int mt = 0; mt < 2; ++mt)
      #pragma unroll
      for (int nt = 0; nt < 4; ++nt)
        acc[mt][nt] = __builtin_amdgcn_mfma_f32_16x16x32_bf16(a[mt], b[nt], acc[mt][nt], 0, 0, 0);
  }
  // + proj_b
  #pragma unroll
  for (int nt = 0; nt < 4; ++nt) {
    int col = wn * 64 + nt * 16 + (lane & 15);
    float pb = proj_b[col];
    #pragma unroll
    for (int mt = 0; mt < 2; ++mt)
      #pragma unroll
      for (int r = 0; r < 4; ++r) acc[mt][nt][r] += pb;
  }
  // phase 3: row stats (LN over 256) without materializing
  #pragma unroll
  for (int mt = 0; mt < 2; ++mt) {
    #pragma unroll
    for (int r = 0; r < 4; ++r) {
      float s = 0.f, q = 0.f;
      #pragma unroll
      for (int nt = 0; nt < 4; ++nt) { float v = acc[mt][nt][r]; s += v; q += v * v; }
      for (int m = 1; m < 16; m <<= 1) { s += __shfl_xor(s, m, 16); q += __shfl_xor(q, m, 16); }
      if ((lane & 15) == 0) {
        int row = wm * 32 + mt * 16 + (lane >> 4) * 4 + r;
        partS[row][wn] = s; partQ[row][wn] = q;
      }
    }
  }
  __syncthreads();
  if (tid < 64) {
    float s = partS[tid][0] + partS[tid][1] + partS[tid][2] + partS[tid][3];
    float q = partQ[tid][0] + partQ[tid][1] + partQ[tid][2] + partQ[tid][3];
    float mean = s * (1.f / 256.f);
    float var = q * (1.f / 256.f) - mean * mean;
    statM[tid] = mean; statI[tid] = rsqrtf(var + 1e-5f);
  }
  __syncthreads();
  #pragma unroll
  for (int nt = 0; nt < 4; ++nt) {
    int col = wn * 64 + nt * 16 + (lane & 15);
    float gc = ln_p_g[col], bc = ln_p_b[col];
    #pragma unroll
    for (int mt = 0; mt < 2; ++mt)
      #pragma unroll
      for (int r = 0; r < 4; ++r) {
        int row = wm * 32 + mt * 16 + (lane >> 4) * 4 + r;
        float v = acc[mt][nt][r];
        float y = (v - statM[row]) * statI[row] * gc + bc;
        float sl = y * sigm(y);
        feat[(size_t)(r0 + row) * 256 + col] = f2bf(sl);
      }
  }
}

// ---------------------------------------------------------------- k3: pre = feat @ WxT + bias4
__global__ __launch_bounds__(256, 2) void gemm_kernel(
    const unsigned short* __restrict__ feat, const unsigned short* __restrict__ WxT,
    const float* __restrict__ bias4, unsigned short* __restrict__ pre)
{
  __shared__ __align__(16) unsigned short Abuf[128 * 64];
  __shared__ __align__(16) unsigned short Bbuf[128 * 64];
  int tid = threadIdx.x, w = tid >> 6, lane = tid & 63;
  int m0 = blockIdx.x * 128, n0 = blockIdx.y * 128;
  int wm = w >> 1, wn = w & 1;
  f32x4 acc[4][4];
  #pragma unroll
  for (int i = 0; i < 4; ++i)
    #pragma unroll
    for (int j = 0; j < 4; ++j) acc[i][j] = (f32x4){0.f, 0.f, 0.f, 0.f};

  int srow = tid >> 3, scc = tid & 7;           // 256 threads cover 32 rows x 8 chunks per iter... (c = i*256+tid)
  (void)srow; (void)scc;
  #pragma unroll 1
  for (int ks = 0; ks < 4; ++ks) {
    int k0 = ks * 64;
    #pragma unroll
    for (int i = 0; i < 4; ++i) {
      int c = i * 256 + tid;
      int row = c >> 3, cc = c & 7;
      const unsigned short* ga = feat + (size_t)(m0 + row) * 256 + (k0 + cc * 8);
      const unsigned short* gb = WxT + (size_t)(n0 + row) * 256 + (k0 + cc * 8);
      char* la = (char*)Abuf + (size_t)(i * 256 + w * 64) * 16;
      char* lb = (char*)Bbuf + (size_t)(i * 256 + w * 64) * 16;
      GLD_LDS16(ga, la);
      GLD_LDS16(gb, lb);
    }
    __syncthreads();
    #pragma unroll
    for (int kk = 0; kk < 2; ++kk) {
      int k = kk * 32 + (lane >> 4) * 8;
      bf16x8 a[4], b[4];
      #pragma unroll
      for (int mt = 0; mt < 4; ++mt) {
        int row = wm * 64 + mt * 16 + (lane & 15);
        a[mt] = *reinterpret_cast<const bf16x8*>(&Abuf[row * 64 + k]);
      }
      #pragma unroll
      for (int nt = 0; nt < 4; ++nt) {
        int col = wn * 64 + nt * 16 + (lane & 15);
        b[nt] = *reinterpret_cast<const bf16x8*>(&Bbuf[col * 64 + k]);
      }
      #pragma unroll
      for (int mt = 0; mt < 4; ++mt)
        #pragma unroll
        for (int nt = 0; nt < 4; ++nt)
          acc[mt][nt] = __builtin_amdgcn_mfma_f32_16x16x32_bf16(a[mt], b[nt], acc[mt][nt], 0, 0, 0);
    }
    __syncthreads();
  }
  #pragma unroll
  for (int nt = 0; nt < 4; ++nt) {
    int col = n0 + wn * 64 + nt * 16 + (lane & 15);
    float bv = bias4[col];
    #pragma unroll
    for (int mt = 0; mt < 4; ++mt)
      #pragma unroll
      for (int r = 0; r < 4; ++r) {
        int row = m0 + wm * 64 + mt * 16 + (lane >> 4) * 4 + r;
        pre[(size_t)row * 1024 + col] = f2bf(acc[mt][nt][r] + bv);
      }
  }
}

// ---------------------------------------------------------------- k4: recurrent scan, 1 WG/batch
__global__ __launch_bounds__(512, 2) void scan_kernel(
    const unsigned short* __restrict__ pre, const float* __restrict__ dt,
    const signed char* __restrict__ wq, const float* __restrict__ sw,
    const float* __restrict__ gW, const float* __restrict__ scal,
    int* __restrict__ hstate, float* __restrict__ out, int s0, int C)
{
  __shared__ int hq[64];          // 256 x int8 h, packed
  __shared__ float gsh[1024];     // gate pre-activations
  __shared__ float red[16];
  int tid = threadIdx.x, w = tid >> 6, lane = tid & 63;
  int b = blockIdx.x;
  int colA = tid, colB = tid + 512;

  int4 wA[16], wB[16];            // resident int8 weights: 2 columns x 256
  {
    const int4* pA = (const int4*)(wq + (size_t)colA * 256);
    const int4* pB = (const int4*)(wq + (size_t)colB * 256);
    #pragma unroll
    for (int i = 0; i < 16; ++i) { wA[i] = pA[i]; wB[i] = pB[i]; }
  }
  float scA = sw[colA] * (1.f / 127.f);
  float scB = sw[colB] * (1.f / 127.f);
  float S_gW = scal[0], S_bW = scal[1];
  float gwv = (tid < 256) ? gW[tid] : 0.f;

  if (tid < 64) hq[tid] = (s0 == 0) ? 0 : hstate[b * 64 + tid];
  __syncthreads();

  const unsigned short* preB = pre + (size_t)b * C * 1024;
  for (int cs = 0; cs < C; ++cs) {
    int s = s0 + cs;
    float pA_ = bf2f(preB[(size_t)cs * 1024 + colA]);
    float pB_ = bf2f(preB[(size_t)cs * 1024 + colB]);
    float dtt = dt[b * SS + s] * 10.f;

    int aA = 0, aB = 0;
    const int4* h4 = (const int4*)hq;
    #pragma unroll
    for (int i = 0; i < 16; ++i) {
      int4 hv = h4[i];
      aA = dot4i8(wA[i].x, hv.x, aA); aA = dot4i8(wA[i].y, hv.y, aA);
      aA = dot4i8(wA[i].z, hv.z, aA); aA = dot4i8(wA[i].w, hv.w, aA);
      aB = dot4i8(wB[i].x, hv.x, aB); aB = dot4i8(wB[i].y, hv.y, aB);
      aB = dot4i8(wB[i].z, hv.z, aB); aB = dot4i8(wB[i].w, hv.w, aB);
    }
    gsh[colA] = (float)aA * scA + pA_;
    gsh[colB] = (float)aB * scB + pB_;
    __syncthreads();

    if (tid < 256) {
      float g0 = gsh[tid], g1 = gsh[tid + 256], g2 = gsh[tid + 512], g3 = gsh[tid + 768];
      float f1 = tanh_f(g0), f2 = tanh_f(g1);
      float ti = sigm(g2 * dtt + g3);
      float h = f1 + ti * (f2 - f1);
      int q = (int)rintf(h * 127.f);
      q = q > 127 ? 127 : (q < -127 ? -127 : q);
      ((signed char*)hq)[tid] = (signed char)q;
      float r1 = h, r2 = h * h, r3 = h * gwv;
      for (int m = 32; m >= 1; m >>= 1) {
        r1 += __shfl_xor(r1, m, 64); r2 += __shfl_xor(r2, m, 64); r3 += __shfl_xor(r3, m, 64);
      }
      if (lane == 0) { red[w * 4] = r1; red[w * 4 + 1] = r2; red[w * 4 + 2] = r3; }
    }
    __syncthreads();

    if (tid == 0) {
      float S1 = red[0] + red[4] + red[8] + red[12];
      float S2 = red[1] + red[5] + red[9] + red[13];
      float S3 = red[2] + red[6] + red[10] + red[14];
      float mean = S1 * (1.f / 256.f);
      float var = S2 * (1.f / 256.f) - mean * mean;
      float inv = rsqrtf(var + 1e-5f);
      out[(size_t)b * SS + s] = inv * (S3 - mean * S_gW) + S_bW;
    }
  }
  __syncthreads();
  if (tid < 64) hstate[b * 64 + tid] = hq[tid];
}

// ---------------------------------------------------------------- launch
extern "C" void kernel_launch(void* const* d_in, const int* in_sizes, int n_in,
                              void* d_out, int out_size, void* d_ws, size_t ws_size,
                              hipStream_t stream)
{
  (void)in_sizes; (void)n_in; (void)out_size;
  const float* x        = (const float*)d_in[0];
  const float* dt       = (const float*)d_in[1];
  const float* ln_in_g  = (const float*)d_in[2];
  const float* ln_in_b  = (const float*)d_in[3];
  const float* proj_W   = (const float*)d_in[4];
  const float* proj_b   = (const float*)d_in[5];
  const float* ln_p_g   = (const float*)d_in[6];
  const float* ln_p_b   = (const float*)d_in[7];
  const float* W_ff1    = (const float*)d_in[8];
  const float* b_ff1    = (const float*)d_in[9];
  const float* W_ff2    = (const float*)d_in[10];
  const float* b_ff2    = (const float*)d_in[11];
  const float* W_ta     = (const float*)d_in[12];
  const float* b_ta     = (const float*)d_in[13];
  const float* W_tb     = (const float*)d_in[14];
  const float* b_tb     = (const float*)d_in[15];
  const float* head_g   = (const float*)d_in[16];
  const float* head_b   = (const float*)d_in[17];
  const float* head_W   = (const float*)d_in[18];
  const float* head_bias= (const float*)d_in[19];

  char* ws = (char*)d_ws;
  unsigned short* WxT = (unsigned short*)(ws + OFF_WXT);
  signed char* wq     = (signed char*)(ws + OFF_WQ);
  float* sw           = (float*)(ws + OFF_SW);
  float* bias4        = (float*)(ws + OFF_BIAS4);
  unsigned short* PWT = (unsigned short*)(ws + OFF_PWT);
  float* gWv          = (float*)(ws + OFF_GW);
  float* scal         = (float*)(ws + OFF_SCAL);
  int* hstate         = (int*)(ws + OFF_HST);

  int C = 16;
  for (int c = 2048; c >= 16; c >>= 1) {
    size_t need = OFF_FEAT + (size_t)c * 65536 + (size_t)c * 262144;
    if (need <= ws_size) { C = c; break; }
  }
  unsigned short* featb = (unsigned short*)(ws + OFF_FEAT);
  unsigned short* preb  = (unsigned short*)(ws + OFF_FEAT + (size_t)C * 65536);
  int cshift = 31 - __builtin_clz((unsigned)C);

  prep_kernel<<<2049, 256, 0, stream>>>(proj_W, W_ff1, b_ff1, W_ff2, b_ff2, W_ta, b_ta, W_tb, b_tb,
                                        head_g, head_b, head_W, head_bias,
                                        WxT, wq, sw, bias4, PWT, gWv, scal);
  int nch = SS / C;
  for (int ch = 0; ch < nch; ++ch) {
    int s0 = ch * C;
    feat_kernel<<<dim3(BB * C / 64), 512, 0, stream>>>(x, ln_in_g, ln_in_b, proj_b, ln_p_g, ln_p_b,
                                                       PWT, featb, s0, C, cshift);
    gemm_kernel<<<dim3(BB * C / 128, 8), 256, 0, stream>>>(featb, WxT, bias4, preb);
    scan_kernel<<<dim3(BB), 512, 0, stream>>>(preb, dt, wq, sw, gWv, scal, hstate,
                                              (float*)d_out, s0, C);
  }
}